// Round 15
// baseline (194.628 us; speedup 1.0000x reference)
//
#include <hip/hip_runtime.h>
#include <hip/hip_bf16.h>

// BitNetAttention: B=2,S=2048,HID=1024,NH=16,HD=64
#define NB 2
#define NS 2048
#define NHID 1024
#define NHEAD 16
#define NHD 64
#define NTOK (NB*NS)        // 4096
#define WELEM (NHID*NHID)   // 1048576

typedef unsigned short u16;
typedef __attribute__((ext_vector_type(4))) float floatx4;
typedef __attribute__((ext_vector_type(16))) float floatx16;
typedef __attribute__((ext_vector_type(8))) __bf16 bf16x8;
typedef __attribute__((ext_vector_type(8))) unsigned short ushort8;
typedef __attribute__((ext_vector_type(4))) unsigned short ushort4v;
typedef __attribute__((ext_vector_type(2))) unsigned uint2v;

__device__ __forceinline__ u16 f2bf(float f) {
  union { float f; unsigned u; } a; a.f = f;
  unsigned u = a.u;
  unsigned r = (u + 0x7fffu + ((u >> 16) & 1u)) >> 16;  // RNE
  return (u16)r;
}
__device__ __forceinline__ float bf2f(u16 s) {
  union { unsigned u; float f; } a; a.u = ((unsigned)s) << 16;
  return a.f;
}
__device__ __forceinline__ void gload16(const void* g, void* lds) {
  __builtin_amdgcn_global_load_lds(
      (const __attribute__((address_space(1))) unsigned int*)g,
      (__attribute__((address_space(3))) unsigned int*)lds, 16, 0, 0);
}
// v_permlane32_swap_b32 builtin: vdst[32:63] <-> src[0:31]; returns {vdst', src'}
__device__ __forceinline__ uint2v pl32(unsigned a, unsigned b) {
  return __builtin_amdgcn_permlane32_swap(a, b, false, false);
}
__device__ __forceinline__ float mergemax(float x) {
  uint2v r = pl32(__float_as_uint(x), __float_as_uint(x));
  return fmaxf(__uint_as_float(r[0]), __uint_as_float(r[1]));
}
// max3-friendly 16-way max (triples fuse to v_max3_f32)
__device__ __forceinline__ float tmax16(const floatx16& v) {
  float a = fmaxf(fmaxf(v[0], v[1]), v[2]);
  float b = fmaxf(fmaxf(v[3], v[4]), v[5]);
  float c = fmaxf(fmaxf(v[6], v[7]), v[8]);
  float d = fmaxf(fmaxf(v[9], v[10]), v[11]);
  float e = fmaxf(fmaxf(v[12], v[13]), v[14]);
  float r0 = fmaxf(fmaxf(a, b), c);
  float r1 = fmaxf(fmaxf(d, e), v[15]);
  return fmaxf(r0, r1);
}

// ---------------- abs-sum reduction (fp64 accumulate for boundary fidelity) --
__global__ void k_abssum(const float* __restrict__ wq, const float* __restrict__ wk,
                         const float* __restrict__ wv, const float* __restrict__ wo,
                         double* __restrict__ sums) {
  const float* srcs[4] = {wq, wk, wv, wo};
  const float* w = srcs[blockIdx.y];
  int idx = (blockIdx.x * 256 + threadIdx.x) * 16;
  float s = 0.f;
#pragma unroll
  for (int j = 0; j < 4; j++) {
    float4 v = *(const float4*)(w + idx + j * 4);
    s += fabsf(v.x) + fabsf(v.y) + fabsf(v.z) + fabsf(v.w);
  }
#pragma unroll
  for (int off = 32; off; off >>= 1) s += __shfl_down(s, off);
  __shared__ float ps[4];
  if ((threadIdx.x & 63) == 0) ps[threadIdx.x >> 6] = s;
  __syncthreads();
  if (threadIdx.x == 0) atomicAdd(&sums[blockIdx.y], (double)(ps[0] + ps[1] + ps[2] + ps[3]));
}

// ------- fused: ternary quantize (4 W) + x hi/lo split + RoPE table ---------
__global__ void k_quantsplit(const float* __restrict__ wq, const float* __restrict__ wk,
                             const float* __restrict__ wv, const float* __restrict__ wo,
                             const double* __restrict__ sums, u16* __restrict__ wt,
                             const float* __restrict__ x,
                             u16* __restrict__ xh, u16* __restrict__ xl,
                             float2* __restrict__ rtab) {
  int bid = blockIdx.x;
  if (bid < 4096) {
    const float* srcs[4] = {wq, wk, wv, wo};
    int y = bid >> 10, xb = bid & 1023;
    const float* w = srcs[y];
    u16* dst = wt + y * WELEM;
    float s = (float)(sums[y] / (double)WELEM) + 1e-5f;
    int idx = (xb * 256 + threadIdx.x) * 4;
    float4 v = *(const float4*)(w + idx);
    float f[4] = {v.x, v.y, v.z, v.w};
    union { u16 ss[4]; uint2 u; } O;
#pragma unroll
    for (int j = 0; j < 4; j++) {
      float q = rintf(f[j] / s);            // round-half-even, matches np.round
      q = fminf(1.f, fmaxf(-1.f, q));
      O.ss[j] = f2bf(q);                    // ternary exact in bf16
    }
    *(uint2*)(dst + idx) = O.u;
  } else if (bid < 8192) {
    int idx = ((bid - 4096) * 256 + threadIdx.x) * 4;
    float4 v = *(const float4*)(x + idx);
    float f[4] = {v.x, v.y, v.z, v.w};
    union { u16 s[4]; uint2 u; } H, L;
#pragma unroll
    for (int j = 0; j < 4; j++) {
      u16 hb = f2bf(f[j]);
      H.s[j] = hb;
      L.s[j] = f2bf(f[j] - bf2f(hb));
    }
    *(uint2*)(xh + idx) = H.u;
    *(uint2*)(xl + idx) = L.u;
  } else {
    // RoPE table: rtab[p*32+d] = (cos(p*inv_d), sin(p*inv_d)), p<2048, d<32
    int idx = (bid - 8192) * 256 + threadIdx.x;   // 65536 entries
    int d = idx & 31;
    float p = (float)(idx >> 5);
    float inv = exp2f((float)d * -0.4152410118609203f);
    float fr = p * inv;
    rtab[idx] = make_float2(cosf(fr), sinf(fr));
  }
}

// ---------------- GEMM + fused epilogues (table RoPE — NO trig calls) -------
template <int MODE>
__global__ __launch_bounds__(256) void k_gemm(
    const u16* __restrict__ Ahi, const u16* __restrict__ Alo,
    const u16* __restrict__ Wt, const int* __restrict__ pos_ids,
    const float2* __restrict__ rtab, float* __restrict__ outf,
    u16* __restrict__ qh, u16* __restrict__ ql,
    u16* __restrict__ kh, u16* __restrict__ kl,
    u16* __restrict__ vt,
    const double* __restrict__ sums, const float* __restrict__ hss) {
  constexpr int BUF = (MODE == 0) ? 24576 : 16384;
  __shared__ __attribute__((aligned(16))) char GSM[2 * BUF];
  const int tid = threadIdx.x;
  const int wave = tid >> 6, lane = tid & 63;
  const int lr = lane & 15, lh = lane >> 4;
  const int bm = blockIdx.x, bn = blockIdx.y, z = blockIdx.z;
  const u16* W = Wt + (MODE == 0 ? z : 3) * WELEM;
  const int wr = wave >> 1, wc = wave & 1;

  floatx4 acc[4][4];
#pragma unroll
  for (int i = 0; i < 4; i++)
#pragma unroll
    for (int j = 0; j < 4; j++) acc[i][j] = (floatx4){0.f, 0.f, 0.f, 0.f};

  const int e0 = tid * 8;
  const int row0 = e0 >> 5, col0 = e0 & 31;

  auto stage = [&](int k0, int nb) {
#pragma unroll
    for (int it = 0; it < 2; ++it) {
      int row = row0 + it * 64;
      gload16(Ahi + (bm * 128 + row) * 1024 + k0 + col0, GSM + nb + it * 4096 + wave * 1024);
      if (MODE == 0 && z != 2)   // V is hi-term only: skip Alo staging
        gload16(Alo + (bm * 128 + row) * 1024 + k0 + col0, GSM + nb + 8192 + it * 4096 + wave * 1024);
      gload16(W + (bn * 128 + row) * 1024 + k0 + col0,
              GSM + nb + (MODE == 0 ? 16384 : 8192) + it * 4096 + wave * 1024);
    }
  };

  stage(0, 0);   // prologue

  for (int kt = 0; kt < 32; ++kt) {  // K = 1024, 32-wide tiles
    __syncthreads();                 // stage(kt) complete; buf[kt-1] readers done
    const int cb = (kt & 1) * BUF;
    if (kt < 31) stage((kt + 1) * 32, ((kt + 1) & 1) * BUF);

    const u16* Ahp = (const u16*)(GSM + cb);
    const u16* Bp  = (const u16*)(GSM + cb + (MODE == 0 ? 16384 : 8192));
    bf16x8 ah[4], bfr[4];
#pragma unroll
    for (int mi = 0; mi < 4; mi++)
      ah[mi] = *(const bf16x8*)(Ahp + (wr * 64 + mi * 16 + lr) * 32 + lh * 8);
#pragma unroll
    for (int ni = 0; ni < 4; ni++)
      bfr[ni] = *(const bf16x8*)(Bp + (wc * 64 + ni * 16 + lr) * 32 + lh * 8);
#pragma unroll
    for (int mi = 0; mi < 4; mi++)
#pragma unroll
      for (int ni = 0; ni < 4; ni++)
        acc[mi][ni] = __builtin_amdgcn_mfma_f32_16x16x32_bf16(ah[mi], bfr[ni], acc[mi][ni], 0, 0, 0);
    if (MODE == 0 && z != 2) {       // V: hi-term only (lo < bf16 rounding of V)
      const u16* Alp = (const u16*)(GSM + cb + 8192);
      bf16x8 al8[4];
#pragma unroll
      for (int mi = 0; mi < 4; mi++)
        al8[mi] = *(const bf16x8*)(Alp + (wr * 64 + mi * 16 + lr) * 32 + lh * 8);
#pragma unroll
      for (int mi = 0; mi < 4; mi++)
#pragma unroll
        for (int ni = 0; ni < 4; ni++)
          acc[mi][ni] = __builtin_amdgcn_mfma_f32_16x16x32_bf16(al8[mi], bfr[ni], acc[mi][ni], 0, 0, 0);
    }
  }

  if (MODE == 1) {
#pragma unroll
    for (int mi = 0; mi < 4; mi++)
#pragma unroll
      for (int ni = 0; ni < 4; ni++)
#pragma unroll
        for (int i = 0; i < 4; i++) {
          int row = bm * 128 + wr * 64 + mi * 16 + lh * 4 + i;
          int col = bn * 128 + wc * 64 + ni * 16 + lr;
          outf[row * 1024 + col] = acc[mi][ni][i];
        }
    if (bm == 0 && bn == 0 && tid == 0) {   // fused out_scale
      float sv = (float)(sums[2] / (double)WELEM) + 1e-5f;
      float so = (float)(sums[3] / (double)WELEM) + 1e-5f;
      outf[NTOK * NHID] = hss[0] * sv * so;
    }
    return;
  }

  const int hh = bn * 2 + wc;          // head (col>>6), independent of ni
  if (z == 2) {
    // ---- V: write directly transposed vt[bh][d][s], 8B packed stores ------
#pragma unroll
    for (int mi = 0; mi < 4; mi++) {
      int row0v = bm * 128 + wr * 64 + mi * 16 + lh * 4;
      int bb = row0v >> 11, s_ = row0v & 2047;
      size_t vbase = ((size_t)(bb * NHEAD + hh)) * (NHD * NS) + s_;
#pragma unroll
      for (int ni = 0; ni < 4; ni++) {
        int hd = ni * 16 + lr;
        union { u16 s4[4]; ushort4v v; } V4;
#pragma unroll
        for (int i = 0; i < 4; i++) V4.s4[i] = f2bf(acc[mi][ni][i]);
        *(ushort4v*)(vt + vbase + (size_t)hd * NS) = V4.v;
      }
    }
    return;
  }

  // ---- Q/K: table-RoPE fused; Q scaled by 0.125*log2(e); hi/lo bf16 out ---
  const float qsc = (z == 0) ? 0.125f * 1.4426950408889634f : 1.0f;
  u16* dh = z ? kh : qh;
  u16* dl = z ? kl : ql;
  int posr[4][4];
#pragma unroll
  for (int mi = 0; mi < 4; mi++)
#pragma unroll
    for (int i = 0; i < 4; i++) {
      int row = bm * 128 + wr * 64 + mi * 16 + lh * 4 + i;
      posr[mi][i] = pos_ids[(row >> 11) * NS + (row & 2047)];
    }
#pragma unroll
  for (int ni = 0; ni < 2; ni++) {
    int d = ni * 16 + lr;                 // 0..31
#pragma unroll
    for (int mi = 0; mi < 4; mi++)
#pragma unroll
      for (int i = 0; i < 4; i++) {
        int row = bm * 128 + wr * 64 + mi * 16 + lh * 4 + i;
        int bb = row >> 11, s_ = row & 2047;
        float2 cs = rtab[posr[mi][i] * 32 + d];
        float x1 = acc[mi][ni][i], x2 = acc[mi][ni + 2][i];
        float n1 = (x1 * cs.x - x2 * cs.y) * qsc;
        float n2 = (x2 * cs.x + x1 * cs.y) * qsc;
        size_t ob = ((size_t)(bb * NHEAD + hh) * NS + s_) * NHD + d;
        u16 h1 = f2bf(n1);
        dh[ob] = h1;      dl[ob] = f2bf(n1 - bf2f(h1));
        u16 h2 = f2bf(n2);
        dh[ob + 32] = h2; dl[ob + 32] = f2bf(n2 - bf2f(h2));
      }
  }
}

// ---------------- flash attention: T15 pipeline (QK(kt+1) || softmax(kt)) ---
// 256 blocks = 32 bh x 8 qt, 512 threads = 8 waves x 32 q-rows. KVBLK=64,
// THREE 24KB LDS buffers (72KB), staging TWO tiles ahead: at each phase,
// tiles kt and kt+1 are resident, so QK(kt+1) [MFMA] issues before
// softmax(kt) [VALU] and the scheduler overlaps them. One barrier per phase.
// Named saccA/saccB (no runtime-indexed score arrays). l via ones-MFMA.
__global__ __launch_bounds__(512) void k_attn(
    const u16* __restrict__ qh, const u16* __restrict__ ql,
    const u16* __restrict__ kh, const u16* __restrict__ kl,
    const u16* __restrict__ vt, u16* __restrict__ aoh) {
  __shared__ __attribute__((aligned(16))) char SM[73728];
  const int tid = threadIdx.x, wave = tid >> 6, lane = tid & 63;
  const int l5 = lane & 31, hi = lane >> 5;
  const int bid = blockIdx.x;
  const int swzb = ((bid & 7) << 5) | (bid >> 3);   // XCD-chunked (256 = 8*32)
  const int qt = swzb & 7, bh = swzb >> 3;
  const int b = bh >> 4, hco = (bh & 15) * NHD;
  const int base = bh * (NS * NHD);
  const int qrow = qt * 256 + wave * 32 + l5;

  // Q B-frags: direct vector loads (pre-scaled, pre-roped)
  bf16x8 qfh[4], qfl[4];
#pragma unroll
  for (int s = 0; s < 4; s++) {
    int off = base + qrow * NHD + s * 16 + hi * 8;
    qfh[s] = *(const bf16x8*)(qh + off);
    qfl[s] = *(const bf16x8*)(ql + off);
  }
  union { ushort8 u; bf16x8 v; } ONES;
#pragma unroll
  for (int j = 0; j < 8; j++) ONES.u[j] = 0x3F80;   // bf16 1.0

  const floatx16 Z16 = {};
  floatx16 acco[2], accl;
  acco[0] = Z16; acco[1] = Z16; accl = Z16;
  float m_r = -1e30f;

  const char* khg0 = (const char*)(kh + base);
  const char* klg0 = (const char*)(kl + base);
  const char* vtg0 = (const char*)(vt + base);   // [64 d-rows][NS], 4096B stride

  // Stage one 24KB tile (Kh 8K | Kl 8K | Vt 8K); 512 thr x 16B per component
#define STAGE_KV(key0_, nb_)                                                     \
  {                                                                              \
    const char* khg = khg0 + (key0_) * 128;                                      \
    const char* klg = klg0 + (key0_) * 128;                                      \
    const char* vtg = vtg0 + (key0_) * 2;                                        \
    int L = tid * 16;                                                            \
    int r7 = (L >> 7) & 7;                                                       \
    int g = L ^ (r7 << 4);                                                       \
    gload16(khg + g, SM + (nb_) + wave * 1024);                                  \
    gload16(klg + g, SM + (nb_) + 8192 + wave * 1024);                           \
    int vcol = (L & 127) ^ (r7 << 4);                                            \
    gload16(vtg + (size_t)(L >> 7) * 4096 + vcol, SM + (nb_) + 16384 + wave * 1024); \
  }

  // QK into sc from buffer kbuf (tile of 64 keys): 24 mfma32
  auto QK = [&](floatx16 (&sc)[2], int kbuf) {
#pragma unroll
    for (int t = 0; t < 2; t++) {
      const int row = 32 * t + l5;
      const int swz = (row & 7) << 4;
      {
        int byt = kbuf + row * 128 + ((hi * 16) ^ swz);
        bf16x8 ah = *(const bf16x8*)(SM + byt);
        bf16x8 al8 = *(const bf16x8*)(SM + 8192 + byt);
        __builtin_amdgcn_s_setprio(1);
        sc[t] = __builtin_amdgcn_mfma_f32_32x32x16_bf16(ah, qfh[0], Z16, 0, 0, 0);
        sc[t] = __builtin_amdgcn_mfma_f32_32x32x16_bf16(ah, qfl[0], sc[t], 0, 0, 0);
        sc[t] = __builtin_amdgcn_mfma_f32_32x32x16_bf16(al8, qfh[0], sc[t], 0, 0, 0);
        __builtin_amdgcn_s_setprio(0);
      }
#pragma unroll
      for (int s = 1; s < 4; s++) {
        int byt = kbuf + row * 128 + ((s * 32 + hi * 16) ^ swz);
        bf16x8 ah = *(const bf16x8*)(SM + byt);
        bf16x8 al8 = *(const bf16x8*)(SM + 8192 + byt);
        __builtin_amdgcn_s_setprio(1);
        sc[t] = __builtin_amdgcn_mfma_f32_32x32x16_bf16(ah, qfh[s], sc[t], 0, 0, 0);
        sc[t] = __builtin_amdgcn_mfma_f32_32x32x16_bf16(ah, qfl[s], sc[t], 0, 0, 0);
        sc[t] = __builtin_amdgcn_mfma_f32_32x32x16_bf16(al8, qfh[s], sc[t], 0, 0, 0);
        __builtin_amdgcn_s_setprio(0);
      }
    }
  };

  // softmax + pack + PV + l-MFMA for tile resident in vbuf
  auto SMPV = [&](floatx16 (&sc)[2], int vbuf) {
    float mt = fmaxf(tmax16(sc[0]), tmax16(sc[1]));
    mt = mergemax(mt);
    if (!__all(mt <= m_r + 8.0f)) {           // defer-max (T13)
      float mn = fmaxf(m_r, mt);
      float sc2 = exp2f(m_r - mn);
      accl[0] *= sc2;
#pragma unroll
      for (int dt = 0; dt < 2; dt++)
#pragma unroll
        for (int r = 0; r < 16; r++) acco[dt][r] *= sc2;
      m_r = mn;
    }
#pragma unroll
    for (int t = 0; t < 2; t++)
#pragma unroll
      for (int r = 0; r < 16; r++)
        sc[t][r] = exp2f(sc[t][r] - m_r);
#pragma unroll
    for (int s = 0; s < 4; s++) {
      int t = s >> 1, rb = (s & 1) * 8;
      union { __bf16 bb[8]; unsigned u[4]; } Wp;
#pragma unroll
      for (int j = 0; j < 8; j++) Wp.bb[j] = (__bf16)sc[t][rb + j];
      uint2v r02 = pl32(Wp.u[0], Wp.u[2]);
      uint2v r13 = pl32(Wp.u[1], Wp.u[3]);
      union { unsigned u[4]; bf16x8 v; } P;
      P.u[0] = r02[0]; P.u[1] = r13[0]; P.u[2] = r02[1]; P.u[3] = r13[1];
      const int swzv0 = (l5 & 7) << 4;
      const int coloff = (s * 32 + hi * 16);
      bf16x8 v0 = *(const bf16x8*)(SM + vbuf + 16384 + l5 * 128 + (coloff ^ swzv0));
      bf16x8 v1 = *(const bf16x8*)(SM + vbuf + 16384 + (l5 + 32) * 128 + (coloff ^ swzv0));
      __builtin_amdgcn_s_setprio(1);
      acco[0] = __builtin_amdgcn_mfma_f32_32x32x16_bf16(v0, P.v, acco[0], 0, 0, 0);
      acco[1] = __builtin_amdgcn_mfma_f32_32x32x16_bf16(v1, P.v, acco[1], 0, 0, 0);
      accl    = __builtin_amdgcn_mfma_f32_32x32x16_bf16(ONES.v, P.v, accl, 0, 0, 0);
      __builtin_amdgcn_s_setprio(0);
    }
  };

  floatx16 saccA[2], saccB[2];

  // prologue: stage tiles 0,1 into bufs 0,1; compute QK(0)
  STAGE_KV(0, 0);
  STAGE_KV(64, 24576);
  __syncthreads();
  QK(saccA, 0);

  int b0 = 0, b1 = 24576, b2 = 49152;
  for (int i = 0; i < 16; ++i) {
    const int kt = 2 * i;
    // ---- phase A: tile kt (sacc in saccA, K/V in b0) ----
    if (i < 15) STAGE_KV((kt + 2) * 64, b2);        // tile kt+2 -> b2
    QK(saccB, b1);                                  // tile kt+1 (MFMA) || softmax below
    SMPV(saccA, b0);                                // softmax+PV tile kt (VALU+MFMA)
    __syncthreads();
    // ---- phase B: tile kt+1 (saccB, b1) ----
    if (i < 15) {
      STAGE_KV((kt + 3) * 64, b0);                  // tile kt+3 -> b0
      QK(saccA, b2);                                // tile kt+2
    }
    SMPV(saccB, b1);
    __syncthreads();
    int t0 = b0; b0 = b2; b2 = b1; b1 = t0;         // (b0,b1,b2) <- (b2,b0,b1)
  }

  // ---- O write: two 128-row rounds through 32KB of LDS -------------------
  float inv = 1.0f / accl[0];   // both lane halves hold identical accl
  float* OT = (float*)SM;
#pragma unroll
  for (int rnd = 0; rnd < 2; rnd++) {
    __syncthreads();
    if ((wave >> 2) == rnd) {
      int orow = (wave & 3) * 32 + l5;
#pragma unroll
      for (int dt = 0; dt < 2; dt++)
#pragma unroll
        for (int r = 0; r < 16; r++) {
          int col = (r & 3) + 8 * (r >> 2) + 4 * hi + 32 * dt;  // d
          int cs = (col & 32) | ((col ^ l5) & 31);
          OT[orow * 64 + cs] = acco[dt][r] * inv;
        }
    }
    __syncthreads();
    {
      int row = tid >> 2, q4 = tid & 3;   // 128 rows, 16 cols per thread
      union { u16 s8[8]; ushort8 v; } HB[2];
#pragma unroll
      for (int j = 0; j < 16; j++) {
        int c = q4 * 16 + j;
        int cs = (c & 32) | ((c ^ (row & 31)) & 31);
        HB[j >> 3].s8[j & 7] = f2bf(OT[row * 64 + cs]);
      }
      int rowg = qt * 256 + rnd * 128 + row;
      size_t doff = ((size_t)(b * NS + rowg)) * NHID + hco + q4 * 16;
      *(ushort8*)(aoh + doff) = HB[0].v;
      *(ushort8*)(aoh + doff + 8) = HB[1].v;
    }
  }
}

extern "C" void kernel_launch(void* const* d_in, const int* in_sizes, int n_in,
                              void* d_out, int out_size, void* d_ws, size_t ws_size,
                              hipStream_t stream) {
  const float* x   = (const float*)d_in[0];
  const float* hss = (const float*)d_in[1];
  const int*   pos = (const int*)d_in[2];
  const float* wq  = (const float*)d_in[3];
  const float* wk  = (const float*)d_in[4];
  const float* wv  = (const float*)d_in[5];
  const float* wo  = (const float*)d_in[6];
  float* out = (float*)d_out;
  char* ws = (char*)d_ws;
  const size_t MB = 1u << 20;
  u16* wt = (u16*)(ws);              // 4 ternary matrices, 8MB
  u16* xh = (u16*)(ws + 8 * MB);
  u16* xl = (u16*)(ws + 16 * MB);
  u16* qh = (u16*)(ws + 24 * MB);
  u16* ql = (u16*)(ws + 32 * MB);
  u16* kh = (u16*)(ws + 40 * MB);
  u16* kl = (u16*)(ws + 48 * MB);
  u16* vt = (u16*)(ws + 56 * MB);    // transposed V [bh][d][s]
  double* sums = (double*)(ws + 72 * MB);
  float2* rtab = (float2*)(ws + 73 * MB);   // 512KB RoPE table
  u16* aoh = xh;   // x dead after k_gemm<0>

  hipMemsetAsync(sums, 0, 4 * sizeof(double), stream);
  k_abssum<<<dim3(256, 4), 256, 0, stream>>>(wq, wk, wv, wo, sums);
  k_quantsplit<<<8448, 256, 0, stream>>>(wq, wk, wv, wo, sums, wt, x, xh, xl, rtab);
  k_gemm<0><<<dim3(32, 8, 3), 256, 0, stream>>>(xh, xl, wt, pos, rtab, nullptr,
                                                qh, ql, kh, kl, vt, nullptr, nullptr);
  k_attn<<<256, 512, 0, stream>>>(qh, ql, kh, kl, vt, aoh);
  k_gemm<1><<<dim3(32, 8, 1), 256, 0, stream>>>(aoh, nullptr, wt, nullptr, nullptr, out,
                                                nullptr, nullptr, nullptr, nullptr, nullptr,
                                                sums, hss);
}

// Round 17
// 179.615 us; speedup vs baseline: 1.0836x; 1.0836x over previous
//
#include <hip/hip_runtime.h>
#include <hip/hip_bf16.h>

// BitNetAttention: B=2,S=2048,HID=1024,NH=16,HD=64
#define NB 2
#define NS 2048
#define NHID 1024
#define NHEAD 16
#define NHD 64
#define NTOK (NB*NS)        // 4096
#define WELEM (NHID*NHID)   // 1048576

typedef unsigned short u16;
typedef __attribute__((ext_vector_type(4))) float floatx4;
typedef __attribute__((ext_vector_type(16))) float floatx16;
typedef __attribute__((ext_vector_type(8))) __bf16 bf16x8;
typedef __attribute__((ext_vector_type(8))) unsigned short ushort8;
typedef __attribute__((ext_vector_type(4))) unsigned short ushort4v;
typedef __attribute__((ext_vector_type(2))) unsigned uint2v;

__device__ __forceinline__ u16 f2bf(float f) {
  union { float f; unsigned u; } a; a.f = f;
  unsigned u = a.u;
  unsigned r = (u + 0x7fffu + ((u >> 16) & 1u)) >> 16;  // RNE
  return (u16)r;
}
__device__ __forceinline__ float bf2f(u16 s) {
  union { unsigned u; float f; } a; a.u = ((unsigned)s) << 16;
  return a.f;
}
__device__ __forceinline__ void gload16(const void* g, void* lds) {
  __builtin_amdgcn_global_load_lds(
      (const __attribute__((address_space(1))) unsigned int*)g,
      (__attribute__((address_space(3))) unsigned int*)lds, 16, 0, 0);
}
// v_permlane32_swap_b32 builtin: vdst[32:63] <-> src[0:31]; returns {vdst', src'}
__device__ __forceinline__ uint2v pl32(unsigned a, unsigned b) {
  return __builtin_amdgcn_permlane32_swap(a, b, false, false);
}
__device__ __forceinline__ float mergemax(float x) {
  uint2v r = pl32(__float_as_uint(x), __float_as_uint(x));
  return fmaxf(__uint_as_float(r[0]), __uint_as_float(r[1]));
}
// max3-friendly 16-way max (triples fuse to v_max3_f32)
__device__ __forceinline__ float tmax16(const floatx16& v) {
  float a = fmaxf(fmaxf(v[0], v[1]), v[2]);
  float b = fmaxf(fmaxf(v[3], v[4]), v[5]);
  float c = fmaxf(fmaxf(v[6], v[7]), v[8]);
  float d = fmaxf(fmaxf(v[9], v[10]), v[11]);
  float e = fmaxf(fmaxf(v[12], v[13]), v[14]);
  float r0 = fmaxf(fmaxf(a, b), c);
  float r1 = fmaxf(fmaxf(d, e), v[15]);
  return fmaxf(r0, r1);
}

// ------ abs-sum stage 1: per-block float partials (NO atomics) --------------
__global__ void k_abssum(const float* __restrict__ wq, const float* __restrict__ wk,
                         const float* __restrict__ wv, const float* __restrict__ wo,
                         float* __restrict__ partials) {
  const float* srcs[4] = {wq, wk, wv, wo};
  const float* w = srcs[blockIdx.y];
  int idx = (blockIdx.x * 256 + threadIdx.x) * 16;
  float s = 0.f;
#pragma unroll
  for (int j = 0; j < 4; j++) {
    float4 v = *(const float4*)(w + idx + j * 4);
    s += fabsf(v.x) + fabsf(v.y) + fabsf(v.z) + fabsf(v.w);
  }
#pragma unroll
  for (int off = 32; off; off >>= 1) s += __shfl_down(s, off);
  __shared__ float ps[4];
  if ((threadIdx.x & 63) == 0) ps[threadIdx.x >> 6] = s;
  __syncthreads();
  if (threadIdx.x == 0)
    partials[blockIdx.y * 256 + blockIdx.x] = ps[0] + ps[1] + ps[2] + ps[3];
}

// ------ abs-sum stage 2: FIXED-ORDER fold -> bitwise-deterministic sums -----
__global__ void k_sumfinal(const float* __restrict__ partials, double* __restrict__ sums) {
  __shared__ double sh[64];
  int y = blockIdx.x, t = threadIdx.x;
  double s = 0.0;
#pragma unroll
  for (int j = 0; j < 4; j++) s += (double)partials[y * 256 + t * 4 + j];
  sh[t] = s;
  __syncthreads();
  if (t == 0) {
    double acc = 0.0;
    for (int i = 0; i < 64; i++) acc += sh[i];
    sums[y] = acc;
  }
}

// ------- fused: ternary quantize (4 W) + x hi/lo split + RoPE table ---------
// Table blocks have NO live MFMA state -> trig calls are safe here.
__global__ void k_quantsplit(const float* __restrict__ wq, const float* __restrict__ wk,
                             const float* __restrict__ wv, const float* __restrict__ wo,
                             const double* __restrict__ sums, u16* __restrict__ wt,
                             const float* __restrict__ x,
                             u16* __restrict__ xh, u16* __restrict__ xl,
                             float2* __restrict__ rtab) {
  int bid = blockIdx.x;
  if (bid < 4096) {
    const float* srcs[4] = {wq, wk, wv, wo};
    int y = bid >> 10, xb = bid & 1023;
    const float* w = srcs[y];
    u16* dst = wt + y * WELEM;
    float s = (float)(sums[y] / (double)WELEM) + 1e-5f;
    int idx = (xb * 256 + threadIdx.x) * 4;
    float4 v = *(const float4*)(w + idx);
    float f[4] = {v.x, v.y, v.z, v.w};
    union { u16 ss[4]; uint2 u; } O;
#pragma unroll
    for (int j = 0; j < 4; j++) {
      float q = rintf(f[j] / s);            // round-half-even, matches np.round
      q = fminf(1.f, fmaxf(-1.f, q));
      O.ss[j] = f2bf(q);                    // ternary exact in bf16
    }
    *(uint2*)(dst + idx) = O.u;
  } else if (bid < 8192) {
    int idx = ((bid - 4096) * 256 + threadIdx.x) * 4;
    float4 v = *(const float4*)(x + idx);
    float f[4] = {v.x, v.y, v.z, v.w};
    union { u16 s[4]; uint2 u; } H, L;
#pragma unroll
    for (int j = 0; j < 4; j++) {
      u16 hb = f2bf(f[j]);
      H.s[j] = hb;
      L.s[j] = f2bf(f[j] - bf2f(hb));
    }
    *(uint2*)(xh + idx) = H.u;
    *(uint2*)(xl + idx) = L.u;
  } else {
    // RoPE table: rtab[p*32+d] = (cos(p*inv_d), sin(p*inv_d)), p<2048, d<32
    int idx = (bid - 8192) * 256 + threadIdx.x;   // 65536 entries
    int d = idx & 31;
    float p = (float)(idx >> 5);
    float inv = exp2f((float)d * -0.4152410118609203f);
    float fr = p * inv;
    rtab[idx] = make_float2(cosf(fr), sinf(fr));
  }
}

// ---------------- GEMM + fused epilogues (table RoPE — NO trig calls) -------
// MODE 0: A = xh+xl (K=2048 eff; V uses hi-term only, skips Alo staging),
//         z selects {q,k,v}. Epilogue: RoPE via rtab; Q scaled by
//         0.125*log2(e); hi/lo bf16 out. V written transposed [bh][d][s].
// MODE 1: A = ao bf16 (K=1024), fp32 store (W_o projection) + out_scale.
template <int MODE>
__global__ __launch_bounds__(256) void k_gemm(
    const u16* __restrict__ Ahi, const u16* __restrict__ Alo,
    const u16* __restrict__ Wt, const int* __restrict__ pos_ids,
    const float2* __restrict__ rtab, float* __restrict__ outf,
    u16* __restrict__ qh, u16* __restrict__ ql,
    u16* __restrict__ kh, u16* __restrict__ kl,
    u16* __restrict__ vt,
    const double* __restrict__ sums, const float* __restrict__ hss) {
  constexpr int BUF = (MODE == 0) ? 24576 : 16384;
  __shared__ __attribute__((aligned(16))) char GSM[2 * BUF];
  const int tid = threadIdx.x;
  const int wave = tid >> 6, lane = tid & 63;
  const int lr = lane & 15, lh = lane >> 4;
  const int bm = blockIdx.x, bn = blockIdx.y, z = blockIdx.z;
  const u16* W = Wt + (MODE == 0 ? z : 3) * WELEM;
  const int wr = wave >> 1, wc = wave & 1;

  floatx4 acc[4][4];
#pragma unroll
  for (int i = 0; i < 4; i++)
#pragma unroll
    for (int j = 0; j < 4; j++) acc[i][j] = (floatx4){0.f, 0.f, 0.f, 0.f};

  const int e0 = tid * 8;
  const int row0 = e0 >> 5, col0 = e0 & 31;

  auto stage = [&](int k0, int nb) {
#pragma unroll
    for (int it = 0; it < 2; ++it) {
      int row = row0 + it * 64;
      gload16(Ahi + (bm * 128 + row) * 1024 + k0 + col0, GSM + nb + it * 4096 + wave * 1024);
      if (MODE == 0 && z != 2)   // V is hi-term only: skip Alo staging
        gload16(Alo + (bm * 128 + row) * 1024 + k0 + col0, GSM + nb + 8192 + it * 4096 + wave * 1024);
      gload16(W + (bn * 128 + row) * 1024 + k0 + col0,
              GSM + nb + (MODE == 0 ? 16384 : 8192) + it * 4096 + wave * 1024);
    }
  };

  stage(0, 0);   // prologue

  for (int kt = 0; kt < 32; ++kt) {  // K = 1024, 32-wide tiles
    __syncthreads();                 // stage(kt) complete; buf[kt-1] readers done
    const int cb = (kt & 1) * BUF;
    if (kt < 31) stage((kt + 1) * 32, ((kt + 1) & 1) * BUF);

    const u16* Ahp = (const u16*)(GSM + cb);
    const u16* Bp  = (const u16*)(GSM + cb + (MODE == 0 ? 16384 : 8192));
    bf16x8 ah[4], bfr[4];
#pragma unroll
    for (int mi = 0; mi < 4; mi++)
      ah[mi] = *(const bf16x8*)(Ahp + (wr * 64 + mi * 16 + lr) * 32 + lh * 8);
#pragma unroll
    for (int ni = 0; ni < 4; ni++)
      bfr[ni] = *(const bf16x8*)(Bp + (wc * 64 + ni * 16 + lr) * 32 + lh * 8);
#pragma unroll
    for (int mi = 0; mi < 4; mi++)
#pragma unroll
      for (int ni = 0; ni < 4; ni++)
        acc[mi][ni] = __builtin_amdgcn_mfma_f32_16x16x32_bf16(ah[mi], bfr[ni], acc[mi][ni], 0, 0, 0);
    if (MODE == 0 && z != 2) {       // V: hi-term only (lo < bf16 rounding of V)
      const u16* Alp = (const u16*)(GSM + cb + 8192);
      bf16x8 al8[4];
#pragma unroll
      for (int mi = 0; mi < 4; mi++)
        al8[mi] = *(const bf16x8*)(Alp + (wr * 64 + mi * 16 + lr) * 32 + lh * 8);
#pragma unroll
      for (int mi = 0; mi < 4; mi++)
#pragma unroll
        for (int ni = 0; ni < 4; ni++)
          acc[mi][ni] = __builtin_amdgcn_mfma_f32_16x16x32_bf16(al8[mi], bfr[ni], acc[mi][ni], 0, 0, 0);
    }
  }

  if (MODE == 1) {
#pragma unroll
    for (int mi = 0; mi < 4; mi++)
#pragma unroll
      for (int ni = 0; ni < 4; ni++)
#pragma unroll
        for (int i = 0; i < 4; i++) {
          int row = bm * 128 + wr * 64 + mi * 16 + lh * 4 + i;
          int col = bn * 128 + wc * 64 + ni * 16 + lr;
          outf[row * 1024 + col] = acc[mi][ni][i];
        }
    if (bm == 0 && bn == 0 && tid == 0) {   // fused out_scale
      float sv = (float)(sums[2] / (double)WELEM) + 1e-5f;
      float so = (float)(sums[3] / (double)WELEM) + 1e-5f;
      outf[NTOK * NHID] = hss[0] * sv * so;
    }
    return;
  }

  const int hh = bn * 2 + wc;          // head (col>>6), independent of ni
  if (z == 2) {
    // ---- V: write directly transposed vt[bh][d][s], 8B packed stores ------
#pragma unroll
    for (int mi = 0; mi < 4; mi++) {
      int row0v = bm * 128 + wr * 64 + mi * 16 + lh * 4;
      int bb = row0v >> 11, s_ = row0v & 2047;
      size_t vbase = ((size_t)(bb * NHEAD + hh)) * (NHD * NS) + s_;
#pragma unroll
      for (int ni = 0; ni < 4; ni++) {
        int hd = ni * 16 + lr;
        union { u16 s4[4]; ushort4v v; } V4;
#pragma unroll
        for (int i = 0; i < 4; i++) V4.s4[i] = f2bf(acc[mi][ni][i]);
        *(ushort4v*)(vt + vbase + (size_t)hd * NS) = V4.v;
      }
    }
    return;
  }

  // ---- Q/K: table-RoPE fused (pair acc[mi][ni] <-> acc[mi][ni+2]), --------
  //      Q scaled by 0.125*log2(e); hi/lo bf16 out. No trig calls -> no spill.
  const float qsc = (z == 0) ? 0.125f * 1.4426950408889634f : 1.0f;
  u16* dh = z ? kh : qh;
  u16* dl = z ? kl : ql;
  int posr[4][4];
#pragma unroll
  for (int mi = 0; mi < 4; mi++)
#pragma unroll
    for (int i = 0; i < 4; i++) {
      int row = bm * 128 + wr * 64 + mi * 16 + lh * 4 + i;
      posr[mi][i] = pos_ids[(row >> 11) * NS + (row & 2047)];
    }
#pragma unroll
  for (int ni = 0; ni < 2; ni++) {
    int d = ni * 16 + lr;                 // 0..31
#pragma unroll
    for (int mi = 0; mi < 4; mi++)
#pragma unroll
      for (int i = 0; i < 4; i++) {
        int row = bm * 128 + wr * 64 + mi * 16 + lh * 4 + i;
        int bb = row >> 11, s_ = row & 2047;
        float2 cs = rtab[posr[mi][i] * 32 + d];
        float x1 = acc[mi][ni][i], x2 = acc[mi][ni + 2][i];
        float n1 = (x1 * cs.x - x2 * cs.y) * qsc;
        float n2 = (x2 * cs.x + x1 * cs.y) * qsc;
        size_t ob = ((size_t)(bb * NHEAD + hh) * NS + s_) * NHD + d;
        u16 h1 = f2bf(n1);
        dh[ob] = h1;      dl[ob] = f2bf(n1 - bf2f(h1));
        u16 h2 = f2bf(n2);
        dh[ob + 32] = h2; dl[ob + 32] = f2bf(n2 - bf2f(h2));
      }
  }
}

// ---------------- flash attention: KVBLK=128, MFMA-computed softmax denom ---
// 256 blocks = 32 bh x 8 qt (XCD-chunked), 512 threads = 8 waves x 32 q-rows.
// 16 KV iterations of 128 keys; dbuf K+V LDS 2x48KB = 96KB (1 block/CU).
// l computed by an extra ones-MFMA per pack slice; max tree in max3 triples.
__global__ __launch_bounds__(512) void k_attn(
    const u16* __restrict__ qh, const u16* __restrict__ ql,
    const u16* __restrict__ kh, const u16* __restrict__ kl,
    const u16* __restrict__ vt, u16* __restrict__ aoh) {
  __shared__ __attribute__((aligned(16))) char SM[98304];
  const int tid = threadIdx.x, wave = tid >> 6, lane = tid & 63;
  const int l5 = lane & 31, hi = lane >> 5;
  const int bid = blockIdx.x;
  const int swzb = ((bid & 7) << 5) | (bid >> 3);   // XCD-chunked (256 = 8*32)
  const int qt = swzb & 7, bh = swzb >> 3;
  const int b = bh >> 4, hco = (bh & 15) * NHD;
  const int base = bh * (NS * NHD);
  const int qrow = qt * 256 + wave * 32 + l5;

  // Q B-frags: direct vector loads (pre-scaled, pre-roped)
  bf16x8 qfh[4], qfl[4];
#pragma unroll
  for (int s = 0; s < 4; s++) {
    int off = base + qrow * NHD + s * 16 + hi * 8;
    qfh[s] = *(const bf16x8*)(qh + off);
    qfl[s] = *(const bf16x8*)(ql + off);
  }
  // ones A-frag for the l-MFMA
  union { ushort8 u; bf16x8 v; } ONES;
#pragma unroll
  for (int j = 0; j < 8; j++) ONES.u[j] = 0x3F80;   // bf16 1.0

  const floatx16 Z16 = {};
  floatx16 acco[2], accl;
  acco[0] = Z16; acco[1] = Z16; accl = Z16;
  float m_r = -1e30f;

  const char* khg0 = (const char*)(kh + base);
  const char* klg0 = (const char*)(kl + base);
  const char* vtg0 = (const char*)(vt + base);   // [64 d-rows][NS], row stride 4096B

  // Stage 48KB tile (Kh 16K | Kl 16K | Vt 16K): 512 threads x 2 its x 16B each
#define STAGE_KV(key0_, nb_)                                                     \
  {                                                                              \
    const char* khg = khg0 + (key0_) * 128;                                      \
    const char* klg = klg0 + (key0_) * 128;                                      \
    const char* vtg = vtg0 + (key0_) * 2;                                        \
    _Pragma("unroll")                                                            \
    for (int it = 0; it < 2; ++it) {                                             \
      int L = it * 8192 + tid * 16;                                              \
      int r7 = (L >> 7) & 7;                                                     \
      int g = L ^ (r7 << 4);                                                     \
      int dst = (nb_) + it * 8192 + wave * 1024;                                 \
      gload16(khg + g, SM + dst);                                                \
      gload16(klg + g, SM + 16384 + dst);                                        \
      int vcol = (L & 255) ^ (((L >> 8) & 15) << 4);                             \
      gload16(vtg + (size_t)(L >> 8) * 4096 + vcol, SM + 32768 + dst);           \
    }                                                                            \
  }

  STAGE_KV(0, 0);   // prologue

  for (int kt = 0; kt < 16; ++kt) {
    __syncthreads();   // stage(kt) landed; buf[kt-1] readers done
    const int cb = (kt & 1) * 49152;
    const int key0 = kt * 128;

    if (kt < 15) STAGE_KV(key0 + 128, ((kt + 1) & 1) * 49152);

    // S^T = K Q^T : 3-term hi/lo, 48 mfma32 over 128 keys
    floatx16 sacc[4];
#pragma unroll
    for (int t = 0; t < 4; t++) {
      const int row = 32 * t + l5;
      const int swz = (row & 7) << 4;
      {
        int byt = cb + row * 128 + ((hi * 16) ^ swz);
        bf16x8 ah = *(const bf16x8*)(SM + byt);
        bf16x8 al8 = *(const bf16x8*)(SM + 16384 + byt);
        __builtin_amdgcn_s_setprio(1);
        sacc[t] = __builtin_amdgcn_mfma_f32_32x32x16_bf16(ah, qfh[0], Z16, 0, 0, 0);
        sacc[t] = __builtin_amdgcn_mfma_f32_32x32x16_bf16(ah, qfl[0], sacc[t], 0, 0, 0);
        sacc[t] = __builtin_amdgcn_mfma_f32_32x32x16_bf16(al8, qfh[0], sacc[t], 0, 0, 0);
        __builtin_amdgcn_s_setprio(0);
      }
#pragma unroll
      for (int s = 1; s < 4; s++) {
        int byt = cb + row * 128 + ((s * 32 + hi * 16) ^ swz);
        bf16x8 ah = *(const bf16x8*)(SM + byt);
        bf16x8 al8 = *(const bf16x8*)(SM + 16384 + byt);
        __builtin_amdgcn_s_setprio(1);
        sacc[t] = __builtin_amdgcn_mfma_f32_32x32x16_bf16(ah, qfh[s], sacc[t], 0, 0, 0);
        sacc[t] = __builtin_amdgcn_mfma_f32_32x32x16_bf16(ah, qfl[s], sacc[t], 0, 0, 0);
        sacc[t] = __builtin_amdgcn_mfma_f32_32x32x16_bf16(al8, qfh[s], sacc[t], 0, 0, 0);
        __builtin_amdgcn_s_setprio(0);
      }
    }

    // ---- in-register online softmax (lane owns q-row = l5) ----------------
    float mt = fmaxf(fmaxf(tmax16(sacc[0]), tmax16(sacc[1])),
                     fmaxf(tmax16(sacc[2]), tmax16(sacc[3])));
    mt = mergemax(mt);                        // lane<->lane+32 merge
    if (!__all(mt <= m_r + 8.0f)) {           // defer-max (T13)
      float mn = fmaxf(m_r, mt);
      float sc2 = exp2f(m_r - mn);
      accl[0] *= sc2;                         // l lives in accl[0]
#pragma unroll
      for (int dt = 0; dt < 2; dt++)
#pragma unroll
        for (int r = 0; r < 16; r++) acco[dt][r] *= sc2;
      m_r = mn;
    }
#pragma unroll
    for (int t = 0; t < 4; t++)
#pragma unroll
      for (int r = 0; r < 16; r++)
        sacc[t][r] = exp2f(sacc[t][r] - m_r);

    // ---- pack P + PV + l-MFMA (V^T frags read per-slice from LDS) ---------
#pragma unroll
    for (int s = 0; s < 8; s++) {
      int t = s >> 1, rb = (s & 1) * 8;
      union { __bf16 bb[8]; unsigned u[4]; } Wp;
#pragma unroll
      for (int j = 0; j < 8; j++) Wp.bb[j] = (__bf16)sacc[t][rb + j];
      uint2v r02 = pl32(Wp.u[0], Wp.u[2]);
      uint2v r13 = pl32(Wp.u[1], Wp.u[3]);
      union { unsigned u[4]; bf16x8 v; } P;
      P.u[0] = r02[0]; P.u[1] = r13[0]; P.u[2] = r02[1]; P.u[3] = r13[1];
      const int coloff = (s * 32 + hi * 16) ^ ((l5 & 15) << 4);
      bf16x8 v0 = *(const bf16x8*)(SM + cb + 32768 + l5 * 256 + coloff);
      bf16x8 v1 = *(const bf16x8*)(SM + cb + 32768 + (l5 + 32) * 256 + coloff);
      __builtin_amdgcn_s_setprio(1);
      acco[0] = __builtin_amdgcn_mfma_f32_32x32x16_bf16(v0, P.v, acco[0], 0, 0, 0);
      acco[1] = __builtin_amdgcn_mfma_f32_32x32x16_bf16(v1, P.v, acco[1], 0, 0, 0);
      accl    = __builtin_amdgcn_mfma_f32_32x32x16_bf16(ONES.v, P.v, accl, 0, 0, 0);
      __builtin_amdgcn_s_setprio(0);
    }
  }

  // ---- O write: two 128-row rounds through 32KB of LDS -------------------
  float inv = 1.0f / accl[0];   // both lane halves hold identical accl
  float* OT = (float*)SM;
#pragma unroll
  for (int rnd = 0; rnd < 2; rnd++) {
    __syncthreads();   // K/V reads done (rnd 0) / prior round reads done
    if ((wave >> 2) == rnd) {
      int orow = (wave & 3) * 32 + l5;
#pragma unroll
      for (int dt = 0; dt < 2; dt++)
#pragma unroll
        for (int r = 0; r < 16; r++) {
          int col = (r & 3) + 8 * (r >> 2) + 4 * hi + 32 * dt;  // d
          int cs = (col & 32) | ((col ^ l5) & 31);
          OT[orow * 64 + cs] = acco[dt][r] * inv;
        }
    }
    __syncthreads();
    {
      int row = tid >> 2, q4 = tid & 3;   // 128 rows, 16 cols per thread
      union { u16 s8[8]; ushort8 v; } HB[2];
#pragma unroll
      for (int j = 0; j < 16; j++) {
        int c = q4 * 16 + j;
        int cs = (c & 32) | ((c ^ (row & 31)) & 31);
        HB[j >> 3].s8[j & 7] = f2bf(OT[row * 64 + cs]);
      }
      int rowg = qt * 256 + rnd * 128 + row;
      size_t doff = ((size_t)(b * NS + rowg)) * NHID + hco + q4 * 16;
      *(ushort8*)(aoh + doff) = HB[0].v;
      *(ushort8*)(aoh + doff + 8) = HB[1].v;
    }
  }
}

extern "C" void kernel_launch(void* const* d_in, const int* in_sizes, int n_in,
                              void* d_out, int out_size, void* d_ws, size_t ws_size,
                              hipStream_t stream) {
  const float* x   = (const float*)d_in[0];
  const float* hss = (const float*)d_in[1];
  const int*   pos = (const int*)d_in[2];
  const float* wq  = (const float*)d_in[3];
  const float* wk  = (const float*)d_in[4];
  const float* wv  = (const float*)d_in[5];
  const float* wo  = (const float*)d_in[6];
  float* out = (float*)d_out;
  char* ws = (char*)d_ws;
  const size_t MB = 1u << 20;
  u16* wt = (u16*)(ws);              // 4 ternary matrices, 8MB
  u16* xh = (u16*)(ws + 8 * MB);
  u16* xl = (u16*)(ws + 16 * MB);
  u16* qh = (u16*)(ws + 24 * MB);
  u16* ql = (u16*)(ws + 32 * MB);
  u16* kh = (u16*)(ws + 40 * MB);
  u16* kl = (u16*)(ws + 48 * MB);
  u16* vt = (u16*)(ws + 56 * MB);    // transposed V [bh][d][s]
  double* sums = (double*)(ws + 72 * MB);
  float2* rtab = (float2*)(ws + 73 * MB);    // 512KB RoPE table
  float* partials = (float*)(ws + 74 * MB);  // 4KB abs-sum partials
  u16* aoh = xh;   // x dead after k_gemm<0>

  k_abssum<<<dim3(256, 4), 256, 0, stream>>>(wq, wk, wv, wo, partials);
  k_sumfinal<<<4, 64, 0, stream>>>(partials, sums);
  k_quantsplit<<<8448, 256, 0, stream>>>(wq, wk, wv, wo, sums, wt, x, xh, xl, rtab);
  k_gemm<0><<<dim3(32, 8, 3), 256, 0, stream>>>(xh, xl, wt, pos, rtab, nullptr,
                                                qh, ql, kh, kl, vt, nullptr, nullptr);
  k_attn<<<256, 512, 0, stream>>>(qh, ql, kh, kl, vt, aoh);
  k_gemm<1><<<dim3(32, 8, 1), 256, 0, stream>>>(aoh, nullptr, wt, nullptr, nullptr, out,
                                                nullptr, nullptr, nullptr, nullptr, nullptr,
                                                sums, hss);
}